// Round 1
// baseline (737.035 us; speedup 1.0000x reference)
//
#include <hip/hip_runtime.h>

#define LOG2E 1.4426950408889634f

__device__ __forceinline__ float rl_f(float v, int lane) {
    return __int_as_float(__builtin_amdgcn_readlane(__float_as_int(v), lane));
}
__device__ __forceinline__ float bperm_f(int byteaddr, float v) {
    return __int_as_float(__builtin_amdgcn_ds_bpermute(byteaddr, __float_as_int(v)));
}
__device__ __forceinline__ float exp2_fast(float x) {
#if __has_builtin(__builtin_amdgcn_exp2f)
    return __builtin_amdgcn_exp2f(x);
#else
    return exp2f(x);
#endif
}
__device__ __forceinline__ float rcp_fast(float x) {
#if __has_builtin(__builtin_amdgcn_rcpf)
    return __builtin_amdgcn_rcpf(x);
#else
    return 1.0f / x;
#endif
}

// One wave (64 lanes) per batch element. Lane g owns gate g:
// lanes 0-15 = i, 16-31 = f, 32-47 = g(tanh), 48-63 = o  (PyTorch order).
// Per step: broadcast h (16 v_readlane -> SGPRs), 16-FMA dot (4-acc tree),
// exp2/rcp activation (input scale folded into weights), 3 ds_bpermute to
// gather f/g/o into quad-0 lanes, c/h update there. h valid in lanes 0..15.
__global__ __launch_bounds__(64, 1) void lstm_seq_kernel(
    const float* __restrict__ x,      // [B, T]
    const int*   __restrict__ x_lens, // [B]
    const float* __restrict__ W_ih,   // [64]
    const float* __restrict__ W_hh,   // [64,16]
    const float* __restrict__ b_ih,   // [64]
    const float* __restrict__ b_hh,   // [64]
    const float* __restrict__ lin_w,  // [2,16]
    const float* __restrict__ lin_b,  // [2]
    float*       __restrict__ out,    // [B,2]
    int T)
{
    const int b    = blockIdx.x;
    const int lane = threadIdx.x;          // 0..63
    const int quad = lane >> 4;

    // Activation-argument scale folded into the linear part:
    //  sigmoid(x) = rcp(1 + exp2(-log2e * x))
    //  tanh(x)    = 2*rcp(1 + exp2(-2*log2e * x)) - 1
    const float s  = (quad == 2) ? (-2.0f * LOG2E) : (-LOG2E);
    const float Aq = (quad == 2) ? 2.0f : 1.0f;
    const float Bq = (quad == 2) ? -1.0f : 0.0f;

    float w[16];
#pragma unroll
    for (int k = 0; k < 16; ++k) w[k] = W_hh[lane * 16 + k] * s;
    const float xc = W_ih[lane] * s;
    const float bc = (b_ih[lane] + b_hh[lane]) * s;

    const int L = x_lens[b];

    // bpermute byte addresses (xor partners; quad0 receives f/g/o)
    const int aF = ((lane ^ 16) << 2);
    const int aG = ((lane ^ 32) << 2);
    const int aO = ((lane ^ 48) << 2);

    float hv = 0.0f;   // h for unit (lane&15); valid in lanes 0..15
    float cv = 0.0f;   // c state; valid in lanes 0..15

    auto step = [&](float xt) {
        // broadcast previous h to SGPRs
        float h0 = rl_f(hv, 0),  h1 = rl_f(hv, 1),  h2 = rl_f(hv, 2),  h3 = rl_f(hv, 3);
        float h4 = rl_f(hv, 4),  h5 = rl_f(hv, 5),  h6 = rl_f(hv, 6),  h7 = rl_f(hv, 7);
        float h8 = rl_f(hv, 8),  h9 = rl_f(hv, 9),  h10 = rl_f(hv, 10), h11 = rl_f(hv, 11);
        float h12 = rl_f(hv, 12), h13 = rl_f(hv, 13), h14 = rl_f(hv, 14), h15 = rl_f(hv, 15);

        float xp = fmaf(xt, xc, bc);
        float a0 = fmaf(h0, w[0],  fmaf(h4, w[4],  fmaf(h8,  w[8],  fmaf(h12, w[12], xp))));
        float a1 = fmaf(h1, w[1],  fmaf(h5, w[5],  fmaf(h9,  w[9],  h13 * w[13])));
        float a2 = fmaf(h2, w[2],  fmaf(h6, w[6],  fmaf(h10, w[10], h14 * w[14])));
        float a3 = fmaf(h3, w[3],  fmaf(h7, w[7],  fmaf(h11, w[11], h15 * w[15])));
        float gate = (a0 + a1) + (a2 + a3);

        float e = exp2_fast(gate);
        float r = rcp_fast(1.0f + e);
        float act = fmaf(Aq, r, Bq);      // sigma for i/f/o lanes, tanh for g lanes

        float sf = bperm_f(aF, act);      // sigma(f_j) into quad0
        float gg = bperm_f(aG, act);      // tanh(g_j) into quad0
        float so = bperm_f(aO, act);      // sigma(o_j) into quad0

        cv = fmaf(sf, cv, act * gg);      // c' = f*c + i*g   (valid in lanes 0..15)
        float e2 = exp2_fast(cv * (-2.0f * LOG2E));
        float th = fmaf(2.0f, rcp_fast(1.0f + e2), -1.0f);
        hv = so * th;                     // h = o * tanh(c)
    };

    // x prefetch: float4 chunks, 2 chunks (8 steps) ahead
    const float4* xv = (const float4*)(x + (size_t)b * T);
    const int Tch = T >> 2;
    float4 xa = xv[0];
    float4 xb = xv[Tch > 1 ? 1 : 0];

    const int full = L >> 2;
    const int rem  = L & 3;
    for (int c = 0; c < full; ++c) {
        int pf = c + 2; if (pf > Tch - 1) pf = Tch - 1;
        float4 xn = xv[pf];
        step(xa.x); step(xa.y); step(xa.z); step(xa.w);
        xa = xb; xb = xn;
    }
    if (rem > 0) step(xa.x);
    if (rem > 1) step(xa.y);
    if (rem > 2) step(xa.z);

    // epilogue: out[b] = lin_w @ h + lin_b
    float o0 = lin_b[0], o1 = lin_b[1];
#pragma unroll
    for (int k = 0; k < 16; ++k) {
        float hk = rl_f(hv, k);
        o0 = fmaf(hk, lin_w[k],      o0);
        o1 = fmaf(hk, lin_w[16 + k], o1);
    }
    if (lane == 0) {
        reinterpret_cast<float2*>(out)[b] = make_float2(o0, o1);
    }
}

extern "C" void kernel_launch(void* const* d_in, const int* in_sizes, int n_in,
                              void* d_out, int out_size, void* d_ws, size_t ws_size,
                              hipStream_t stream) {
    const float* x      = (const float*)d_in[0];
    const int*   x_lens = (const int*)  d_in[1];
    const float* W_ih   = (const float*)d_in[2];
    const float* W_hh   = (const float*)d_in[3];
    const float* b_ih   = (const float*)d_in[4];
    const float* b_hh   = (const float*)d_in[5];
    const float* lin_w  = (const float*)d_in[6];
    const float* lin_b  = (const float*)d_in[7];
    float* out = (float*)d_out;

    const int B = in_sizes[1];
    const int T = in_sizes[0] / B;

    lstm_seq_kernel<<<B, 64, 0, stream>>>(x, x_lens, W_ih, W_hh, b_ih, b_hh,
                                          lin_w, lin_b, out, T);
}

// Round 2
// 532.147 us; speedup vs baseline: 1.3850x; 1.3850x over previous
//
#include <hip/hip_runtime.h>

#define LOG2E 1.4426950408889634f
#define NEG2LOG2E (-2.8853900817779268f)  // -2*log2(e)

__device__ __forceinline__ float rl_f(float v, int lane) {
    return __int_as_float(__builtin_amdgcn_readlane(__float_as_int(v), lane));
}

template<int CTRL>
__device__ __forceinline__ float dpp_bcast(float v) {
    // quad_perm broadcast within groups of 4 lanes; all lanes active.
    return __int_as_float(__builtin_amdgcn_mov_dpp(__float_as_int(v), CTRL, 0xF, 0xF, false));
}

__device__ __forceinline__ float exp2_fast(float x) {
#if __has_builtin(__builtin_amdgcn_exp2f)
    return __builtin_amdgcn_exp2f(x);
#else
    return exp2f(x);
#endif
}
__device__ __forceinline__ float rcp_fast(float x) {
#if __has_builtin(__builtin_amdgcn_rcpf)
    return __builtin_amdgcn_rcpf(x);
#else
    return 1.0f / x;
#endif
}

// One wave per batch. Interleaved layout: lane = 4*unit + gate,
// gate 0=i, 1=f, 2=g(tanh), 3=o (PyTorch row order: W rows g*16+u).
// Per step: 16 v_readlane h-broadcast -> 16-FMA dot (4-acc tree) ->
// exp2/rcp activation (arg scale folded into weights; i-gate additionally
// carries -2log2e so c stays in tanh-arg-scaled space) -> 4 DPP quad_perm
// broadcasts (VALU latency, replaces ds_bpermute ~120cyc) -> replicated
// c/h update in every lane.
__global__ __launch_bounds__(64, 1) void lstm_seq_kernel(
    const float* __restrict__ x,      // [B, T]
    const int*   __restrict__ x_lens, // [B]
    const float* __restrict__ W_ih,   // [64]
    const float* __restrict__ W_hh,   // [64,16]
    const float* __restrict__ b_ih,   // [64]
    const float* __restrict__ b_hh,   // [64]
    const float* __restrict__ lin_w,  // [2,16]
    const float* __restrict__ lin_b,  // [2]
    float*       __restrict__ out,    // [B,2]
    int T)
{
    const int b    = blockIdx.x;
    const int lane = threadIdx.x;      // 0..63
    const int gate = lane & 3;         // 0=i,1=f,2=g,3=o
    const int unit = lane >> 2;        // 0..15
    const int row  = gate * 16 + unit; // row in the 4H-stacked weight

    // sigmoid(x) = rcp(1 + exp2(-log2e*x)); tanh(x) = 2*rcp(1+exp2(-2log2e*x)) - 1
    const float s  = (gate == 2) ? (2.0f * NEG2LOG2E * 0.5f) : (-LOG2E); // g-gate: -2log2e
    // activation = Aq*rcp(1+exp2(s*pre)) + Bq ; i-gate result additionally
    // scaled by NEG2LOG2E (c kept in scaled space), folded into Aq/Bq.
    float Aq = (gate == 2) ? 2.0f : 1.0f;
    float Bq = (gate == 2) ? -1.0f : 0.0f;
    if (gate == 0) { Aq *= NEG2LOG2E; Bq *= NEG2LOG2E; }

    // --- load weights into named registers and pin them ---
    const float* wr = W_hh + row * 16;
    float w0  = wr[0]  * s, w1  = wr[1]  * s, w2  = wr[2]  * s, w3  = wr[3]  * s;
    float w4  = wr[4]  * s, w5  = wr[5]  * s, w6  = wr[6]  * s, w7  = wr[7]  * s;
    float w8  = wr[8]  * s, w9  = wr[9]  * s, w10 = wr[10] * s, w11 = wr[11] * s;
    float w12 = wr[12] * s, w13 = wr[13] * s, w14 = wr[14] * s, w15 = wr[15] * s;
    float xc = W_ih[row] * s;
    float bc = (b_ih[row] + b_hh[row]) * s;
    // Pin: opaque to the optimizer -> values must be materialized in VGPRs
    // here and cannot be re-loaded from memory inside the loop.
    asm volatile("" : "+v"(w0), "+v"(w1), "+v"(w2), "+v"(w3),
                      "+v"(w4), "+v"(w5), "+v"(w6), "+v"(w7),
                      "+v"(w8), "+v"(w9), "+v"(w10), "+v"(w11),
                      "+v"(w12), "+v"(w13), "+v"(w14), "+v"(w15),
                      "+v"(xc), "+v"(bc));

    const int L = x_lens[b];

    float hv = 0.0f;   // h_unit, replicated across the 4 lanes of the quad
    float cs = 0.0f;   // c_unit * NEG2LOG2E (scaled space), replicated

    auto step = [&](float xt) {
        // broadcast previous h (unit j lives in lanes 4j..4j+3)
        float h0  = rl_f(hv, 0),  h1  = rl_f(hv, 4),  h2  = rl_f(hv, 8),  h3  = rl_f(hv, 12);
        float h4  = rl_f(hv, 16), h5  = rl_f(hv, 20), h6  = rl_f(hv, 24), h7  = rl_f(hv, 28);
        float h8  = rl_f(hv, 32), h9  = rl_f(hv, 36), h10 = rl_f(hv, 40), h11 = rl_f(hv, 44);
        float h12 = rl_f(hv, 48), h13 = rl_f(hv, 52), h14 = rl_f(hv, 56), h15 = rl_f(hv, 60);

        float xp = fmaf(xt, xc, bc);
        float a0 = fmaf(h0, w0,  fmaf(h4, w4,  fmaf(h8,  w8,  fmaf(h12, w12, xp))));
        float a1 = fmaf(h1, w1,  fmaf(h5, w5,  fmaf(h9,  w9,  h13 * w13)));
        float a2 = fmaf(h2, w2,  fmaf(h6, w6,  fmaf(h10, w10, h14 * w14)));
        float a3 = fmaf(h3, w3,  fmaf(h7, w7,  fmaf(h11, w11, h15 * w15)));
        float pre = (a0 + a1) + (a2 + a3);

        float e   = exp2_fast(pre);
        float r   = rcp_fast(1.0f + e);
        float act = fmaf(Aq, r, Bq);  // i: k*sigma(i); f,o: sigma; g: tanh

        float si = dpp_bcast<0x00>(act);  // k*sigma(i_u)  -> all 4 lanes
        float sf = dpp_bcast<0x55>(act);  // sigma(f_u)
        float gg = dpp_bcast<0xAA>(act);  // tanh(g_u)
        float so = dpp_bcast<0xFF>(act);  // sigma(o_u)

        cs = fmaf(sf, cs, si * gg);            // k*c' = f*(k*c) + (k*i)*g
        float th = fmaf(2.0f, rcp_fast(1.0f + exp2_fast(cs)), -1.0f); // tanh(c')
        hv = so * th;
    };

    // x prefetch: float4 chunks, 2 chunks (8 steps) ahead
    const float4* xv = (const float4*)(x + (size_t)b * T);
    const int Tch = T >> 2;
    float4 xa = xv[0];
    float4 xb = xv[Tch > 1 ? 1 : 0];

    const int full = L >> 2;
    const int rem  = L & 3;
    for (int c = 0; c < full; ++c) {
        int pf = c + 2; if (pf > Tch - 1) pf = Tch - 1;
        float4 xn = xv[pf];
        step(xa.x); step(xa.y); step(xa.z); step(xa.w);
        xa = xb; xb = xn;
    }
    if (rem > 0) step(xa.x);
    if (rem > 1) step(xa.y);
    if (rem > 2) step(xa.z);

    // epilogue: out[b] = lin_w @ h + lin_b   (h_j replicated in lanes 4j..4j+3)
    float o0 = lin_b[0], o1 = lin_b[1];
#pragma unroll
    for (int k = 0; k < 16; ++k) {
        float hk = rl_f(hv, 4 * k);
        o0 = fmaf(hk, lin_w[k],      o0);
        o1 = fmaf(hk, lin_w[16 + k], o1);
    }
    if (lane == 0) {
        reinterpret_cast<float2*>(out)[b] = make_float2(o0, o1);
    }
}

extern "C" void kernel_launch(void* const* d_in, const int* in_sizes, int n_in,
                              void* d_out, int out_size, void* d_ws, size_t ws_size,
                              hipStream_t stream) {
    const float* x      = (const float*)d_in[0];
    const int*   x_lens = (const int*)  d_in[1];
    const float* W_ih   = (const float*)d_in[2];
    const float* W_hh   = (const float*)d_in[3];
    const float* b_ih   = (const float*)d_in[4];
    const float* b_hh   = (const float*)d_in[5];
    const float* lin_w  = (const float*)d_in[6];
    const float* lin_b  = (const float*)d_in[7];
    float* out = (float*)d_out;

    const int B = in_sizes[1];
    const int T = in_sizes[0] / B;

    lstm_seq_kernel<<<B, 64, 0, stream>>>(x, x_lens, W_ih, W_hh, b_ih, b_hh,
                                          lin_w, lin_b, out, T);
}

// Round 4
// 484.286 us; speedup vs baseline: 1.5219x; 1.0988x over previous
//
#include <hip/hip_runtime.h>

#define LOG2E 1.4426950408889634f
#define NEG2LOG2E (-2.8853900817779268f)  // -2*log2(e)

typedef __fp16 h2_t __attribute__((ext_vector_type(2)));

__device__ __forceinline__ float rl_f(float v, int lane) {
    return __int_as_float(__builtin_amdgcn_readlane(__float_as_int(v), lane));
}
__device__ __forceinline__ int bc_i(h2_t v) { union { h2_t h; int i; } u; u.h = v; return u.i; }
__device__ __forceinline__ h2_t bc_h(int v) { union { h2_t h; int i; } u; u.i = v; return u.h; }

template<int CTRL>
__device__ __forceinline__ float dpp_f(float v) {
    return __int_as_float(__builtin_amdgcn_mov_dpp(__float_as_int(v), CTRL, 0xF, 0xF, true));
}

__device__ __forceinline__ float exp2_fast(float x) {
#if __has_builtin(__builtin_amdgcn_exp2f)
    return __builtin_amdgcn_exp2f(x);
#else
    return exp2f(x);
#endif
}
__device__ __forceinline__ float rcp_fast(float x) {
#if __has_builtin(__builtin_amdgcn_rcpf)
    return __builtin_amdgcn_rcpf(x);
#else
    return 1.0f / x;
#endif
}
__device__ __forceinline__ float fdot2(h2_t a, h2_t b, float c) {
#if __has_builtin(__builtin_amdgcn_fdot2)
    return __builtin_amdgcn_fdot2(a, b, c, false);
#else
    return c + (float)a.x * (float)b.x + (float)a.y * (float)b.y;
#endif
}

// One wave per batch. lane = 4*unit + gate (gate 0=i,1=f,2=g,3=o).
// h carried cross-lane as packed f16 pairs: DPP row_shl:4 brings unit u+1's h
// into unit u's lane, cvt_pkrtz packs (h_{2k},h_{2k+1}); 8 v_readlane -> SGPRs;
// dot = 8 v_dot2_f32_f16 against packed f16 weights (fp32 accumulate).
// c stays fp32 per-lane (never crosses lanes). Activation arg scales folded
// into weights; i-gate carries -2log2e so c lives in tanh-arg-scaled space.
__global__ __launch_bounds__(64, 1) void lstm_seq_kernel(
    const float* __restrict__ x,      // [B, T]
    const int*   __restrict__ x_lens, // [B]
    const float* __restrict__ W_ih,   // [64]
    const float* __restrict__ W_hh,   // [64,16]
    const float* __restrict__ b_ih,   // [64]
    const float* __restrict__ b_hh,   // [64]
    const float* __restrict__ lin_w,  // [2,16]
    const float* __restrict__ lin_b,  // [2]
    float*       __restrict__ out,    // [B,2]
    int T)
{
    const int b    = blockIdx.x;
    const int lane = threadIdx.x;      // 0..63
    const int gate = lane & 3;         // 0=i,1=f,2=g,3=o
    const int unit = lane >> 2;        // 0..15
    const int row  = gate * 16 + unit;

    const float s  = (gate == 2) ? NEG2LOG2E : (-LOG2E);
    float Aq = (gate == 2) ? 2.0f : 1.0f;
    float Bq = (gate == 2) ? -1.0f : 0.0f;
    if (gate == 0) { Aq *= NEG2LOG2E; Bq *= NEG2LOG2E; }

    // --- pack scaled weights into f16 pairs, pin in VGPRs ---
    const float* wr = W_hh + row * 16;
    int wp0 = bc_i(__builtin_amdgcn_cvt_pkrtz(wr[0]  * s, wr[1]  * s));
    int wp1 = bc_i(__builtin_amdgcn_cvt_pkrtz(wr[2]  * s, wr[3]  * s));
    int wp2 = bc_i(__builtin_amdgcn_cvt_pkrtz(wr[4]  * s, wr[5]  * s));
    int wp3 = bc_i(__builtin_amdgcn_cvt_pkrtz(wr[6]  * s, wr[7]  * s));
    int wp4 = bc_i(__builtin_amdgcn_cvt_pkrtz(wr[8]  * s, wr[9]  * s));
    int wp5 = bc_i(__builtin_amdgcn_cvt_pkrtz(wr[10] * s, wr[11] * s));
    int wp6 = bc_i(__builtin_amdgcn_cvt_pkrtz(wr[12] * s, wr[13] * s));
    int wp7 = bc_i(__builtin_amdgcn_cvt_pkrtz(wr[14] * s, wr[15] * s));
    float xc = W_ih[row] * s;
    float bcn = (b_ih[row] + b_hh[row]) * s;
    asm volatile("" : "+v"(wp0), "+v"(wp1), "+v"(wp2), "+v"(wp3),
                      "+v"(wp4), "+v"(wp5), "+v"(wp6), "+v"(wp7),
                      "+v"(xc), "+v"(bcn));

    const int L = x_lens[b];

    float hv = 0.0f;   // h_unit (fp32), replicated across the quad
    float cs = 0.0f;   // c_unit * NEG2LOG2E, replicated

    auto step = [&](float xt) {
        // pack (h_{2k}, h_{2k+1}): partner = unit+1, 4 lanes up -> row_shl:4
        float part = dpp_f<0x104>(hv);
        int hpi = bc_i(__builtin_amdgcn_cvt_pkrtz(hv, part));
        // pair k lives in lane 8k (unit 2k, gate 0)
        int s0 = __builtin_amdgcn_readlane(hpi, 0);
        int s1 = __builtin_amdgcn_readlane(hpi, 8);
        int s2 = __builtin_amdgcn_readlane(hpi, 16);
        int s3 = __builtin_amdgcn_readlane(hpi, 24);
        int s4 = __builtin_amdgcn_readlane(hpi, 32);
        int s5 = __builtin_amdgcn_readlane(hpi, 40);
        int s6 = __builtin_amdgcn_readlane(hpi, 48);
        int s7 = __builtin_amdgcn_readlane(hpi, 56);

        float xp = fmaf(xt, xc, bcn);
        float a0 = fdot2(bc_h(s0), bc_h(wp0), xp);
        float a1 = fdot2(bc_h(s1), bc_h(wp1), 0.0f);
        a0 = fdot2(bc_h(s2), bc_h(wp2), a0);
        a1 = fdot2(bc_h(s3), bc_h(wp3), a1);
        a0 = fdot2(bc_h(s4), bc_h(wp4), a0);
        a1 = fdot2(bc_h(s5), bc_h(wp5), a1);
        a0 = fdot2(bc_h(s6), bc_h(wp6), a0);
        a1 = fdot2(bc_h(s7), bc_h(wp7), a1);
        float pre = a0 + a1;

        float e   = exp2_fast(pre);
        float r   = rcp_fast(1.0f + e);
        float act = fmaf(Aq, r, Bq);  // i: k*sigma; f,o: sigma; g: tanh

        float si = dpp_f<0x00>(act);
        float sf = dpp_f<0x55>(act);
        float gg = dpp_f<0xAA>(act);
        float so = dpp_f<0xFF>(act);

        cs = fmaf(sf, cs, si * gg);                                   // k*c'
        float th = fmaf(2.0f, rcp_fast(1.0f + exp2_fast(cs)), -1.0f); // tanh(c')
        hv = so * th;
    };

    const float4* xv = (const float4*)(x + (size_t)b * T);
    const int Tch = T >> 2;
    float4 xa = xv[0];
    float4 xb = xv[Tch > 1 ? 1 : 0];

    const int full = L >> 2;
    const int rem  = L & 3;
    for (int c = 0; c < full; ++c) {
        int pf = c + 2; if (pf > Tch - 1) pf = Tch - 1;
        float4 xn = xv[pf];
        step(xa.x); step(xa.y); step(xa.z); step(xa.w);
        xa = xb; xb = xn;
    }
    if (rem > 0) step(xa.x);
    if (rem > 1) step(xa.y);
    if (rem > 2) step(xa.z);

    // epilogue: out[b] = lin_w @ h + lin_b  (h_u replicated in lanes 4u..4u+3)
    float o0 = lin_b[0], o1 = lin_b[1];
#pragma unroll
    for (int k = 0; k < 16; ++k) {
        float hk = rl_f(hv, 4 * k);
        o0 = fmaf(hk, lin_w[k],      o0);
        o1 = fmaf(hk, lin_w[16 + k], o1);
    }
    if (lane == 0) {
        reinterpret_cast<float2*>(out)[b] = make_float2(o0, o1);
    }
}

extern "C" void kernel_launch(void* const* d_in, const int* in_sizes, int n_in,
                              void* d_out, int out_size, void* d_ws, size_t ws_size,
                              hipStream_t stream) {
    const float* x      = (const float*)d_in[0];
    const int*   x_lens = (const int*)  d_in[1];
    const float* W_ih   = (const float*)d_in[2];
    const float* W_hh   = (const float*)d_in[3];
    const float* b_ih   = (const float*)d_in[4];
    const float* b_hh   = (const float*)d_in[5];
    const float* lin_w  = (const float*)d_in[6];
    const float* lin_b  = (const float*)d_in[7];
    float* out = (float*)d_out;

    const int B = in_sizes[1];
    const int T = in_sizes[0] / B;

    lstm_seq_kernel<<<B, 64, 0, stream>>>(x, x_lens, W_ih, W_hh, b_ih, b_hh,
                                          lin_w, lin_b, out, T);
}

// Round 5
// 474.624 us; speedup vs baseline: 1.5529x; 1.0204x over previous
//
#include <hip/hip_runtime.h>

#define LOG2E 1.4426950408889634f
#define NEG2LOG2E (-2.8853900817779268f)  // -2*log2(e)

typedef __fp16 h2_t __attribute__((ext_vector_type(2)));

__device__ __forceinline__ float rl_f(float v, int lane) {
    return __int_as_float(__builtin_amdgcn_readlane(__float_as_int(v), lane));
}
__device__ __forceinline__ int bc_i(h2_t v) { union { h2_t h; int i; } u; u.h = v; return u.i; }
__device__ __forceinline__ h2_t bc_h(int v) { union { h2_t h; int i; } u; u.i = v; return u.h; }

template<int CTRL>
__device__ __forceinline__ float dpp_f(float v) {
    return __int_as_float(__builtin_amdgcn_mov_dpp(__float_as_int(v), CTRL, 0xF, 0xF, true));
}

__device__ __forceinline__ float exp2_fast(float x) {
#if __has_builtin(__builtin_amdgcn_exp2f)
    return __builtin_amdgcn_exp2f(x);
#else
    return exp2f(x);
#endif
}
__device__ __forceinline__ float rcp_fast(float x) {
#if __has_builtin(__builtin_amdgcn_rcpf)
    return __builtin_amdgcn_rcpf(x);
#else
    return 1.0f / x;
#endif
}
__device__ __forceinline__ float fdot2(h2_t a, h2_t b, float c) {
#if __has_builtin(__builtin_amdgcn_fdot2)
    return __builtin_amdgcn_fdot2(a, b, c, false);
#else
    return c + (float)a.x * (float)b.x + (float)a.y * (float)b.y;
#endif
}

// One wave per batch. lane = 4*unit + gate (gate 0=i,1=f,2=g,3=o).
// Latency-bound serial recurrence; everything optimized for the dependent
// cycle: c -> exp2/rcp (tanh) -> h (single fused fma) -> DPP pack ->
// 8 readlane -> 4x2 dot tree -> exp2/rcp (gate act) -> DPP bcast -> c.
__global__ __launch_bounds__(64, 1) void lstm_seq_kernel(
    const float* __restrict__ x,      // [B, T]
    const int*   __restrict__ x_lens, // [B]
    const float* __restrict__ W_ih,   // [64]
    const float* __restrict__ W_hh,   // [64,16]
    const float* __restrict__ b_ih,   // [64]
    const float* __restrict__ b_hh,   // [64]
    const float* __restrict__ lin_w,  // [2,16]
    const float* __restrict__ lin_b,  // [2]
    float*       __restrict__ out,    // [B,2]
    int T)
{
    const int b    = blockIdx.x;
    const int lane = threadIdx.x;      // 0..63
    const int gate = lane & 3;         // 0=i,1=f,2=g,3=o
    const int unit = lane >> 2;        // 0..15
    const int row  = gate * 16 + unit;

    const float s  = (gate == 2) ? NEG2LOG2E : (-LOG2E);
    float Aq = (gate == 2) ? 2.0f : 1.0f;
    float Bq = (gate == 2) ? -1.0f : 0.0f;
    if (gate == 0) { Aq *= NEG2LOG2E; Bq *= NEG2LOG2E; }

    // --- pack scaled weights into f16 pairs, pin in VGPRs ---
    const float* wr = W_hh + row * 16;
    int wp0 = bc_i(__builtin_amdgcn_cvt_pkrtz(wr[0]  * s, wr[1]  * s));
    int wp1 = bc_i(__builtin_amdgcn_cvt_pkrtz(wr[2]  * s, wr[3]  * s));
    int wp2 = bc_i(__builtin_amdgcn_cvt_pkrtz(wr[4]  * s, wr[5]  * s));
    int wp3 = bc_i(__builtin_amdgcn_cvt_pkrtz(wr[6]  * s, wr[7]  * s));
    int wp4 = bc_i(__builtin_amdgcn_cvt_pkrtz(wr[8]  * s, wr[9]  * s));
    int wp5 = bc_i(__builtin_amdgcn_cvt_pkrtz(wr[10] * s, wr[11] * s));
    int wp6 = bc_i(__builtin_amdgcn_cvt_pkrtz(wr[12] * s, wr[13] * s));
    int wp7 = bc_i(__builtin_amdgcn_cvt_pkrtz(wr[14] * s, wr[15] * s));
    float xc  = W_ih[row] * s;
    float bcn = (b_ih[row] + b_hh[row]) * s;
    asm volatile("" : "+v"(wp0), "+v"(wp1), "+v"(wp2), "+v"(wp3),
                      "+v"(wp4), "+v"(wp5), "+v"(wp6), "+v"(wp7),
                      "+v"(xc), "+v"(bcn));

    const int L = x_lens[b];

    float hv = 0.0f;   // h_unit (fp32), replicated across the quad
    float cs = 0.0f;   // c_unit * NEG2LOG2E, replicated

    auto step = [&](float xt) {
        // pack (h_{2k}, h_{2k+1}): partner = unit+1 -> row_shl:4
        float part = dpp_f<0x104>(hv);
        int hpi = bc_i(__builtin_amdgcn_cvt_pkrtz(hv, part));
        // pair k lives in lane 8k (unit 2k, gate 0); first-needed first
        int s0 = __builtin_amdgcn_readlane(hpi, 0);
        int s1 = __builtin_amdgcn_readlane(hpi, 8);
        int s2 = __builtin_amdgcn_readlane(hpi, 16);
        int s3 = __builtin_amdgcn_readlane(hpi, 24);
        int s4 = __builtin_amdgcn_readlane(hpi, 32);
        int s5 = __builtin_amdgcn_readlane(hpi, 40);
        int s6 = __builtin_amdgcn_readlane(hpi, 48);
        int s7 = __builtin_amdgcn_readlane(hpi, 56);

        float xp = fmaf(xt, xc, bcn);              // off-path
        float a0 = fdot2(bc_h(s0), bc_h(wp0), xp);
        float a1 = fdot2(bc_h(s1), bc_h(wp1), 0.0f);
        float a2 = fdot2(bc_h(s2), bc_h(wp2), 0.0f);
        float a3 = fdot2(bc_h(s3), bc_h(wp3), 0.0f);
        a0 = fdot2(bc_h(s4), bc_h(wp4), a0);
        a1 = fdot2(bc_h(s5), bc_h(wp5), a1);
        a2 = fdot2(bc_h(s6), bc_h(wp6), a2);
        a3 = fdot2(bc_h(s7), bc_h(wp7), a3);
        float pre = (a0 + a1) + (a2 + a3);         // depth-2 tree

        float e   = exp2_fast(pre);
        float r   = rcp_fast(1.0f + e);
        float act = fmaf(Aq, r, Bq);  // i: k*sigma; f,o: sigma; g: tanh

        float si = dpp_f<0x00>(act);
        float sf = dpp_f<0x55>(act);
        float gg = dpp_f<0xAA>(act);
        float so = dpp_f<0xFF>(act);
        float so2 = so + so;                       // off-path

        cs = fmaf(sf, cs, si * gg);                // k*c'
        float r2 = rcp_fast(1.0f + exp2_fast(cs));
        hv = fmaf(so2, r2, -so);                   // h = o*tanh(c), fused
    };

    // 8 steps per iteration; prefetch next pair of float4 one iter ahead
    const float4* xv = (const float4*)(x + (size_t)b * T);
    const int nPairs = T >> 3;                     // float4-pairs (8 steps each)
    float4 xa = xv[0];
    float4 xb = xv[1];

    const int full = L >> 3;
    for (int it = 0; it < full; ++it) {
        int nx = it + 1; if (nx > nPairs - 1) nx = nPairs - 1;
        float4 na = xv[2 * nx];
        float4 nb = xv[2 * nx + 1];
        step(xa.x); step(xa.y); step(xa.z); step(xa.w);
        step(xb.x); step(xb.y); step(xb.z); step(xb.w);
        xa = na; xb = nb;
    }
    // tail (<8 steps): current pair xa/xb covers steps [8*full, 8*full+8)
    const int rem = L & 7;
    if (rem > 0) step(xa.x);
    if (rem > 1) step(xa.y);
    if (rem > 2) step(xa.z);
    if (rem > 3) step(xa.w);
    if (rem > 4) step(xb.x);
    if (rem > 5) step(xb.y);
    if (rem > 6) step(xb.z);

    // epilogue: out[b] = lin_w @ h + lin_b  (h_u replicated in lanes 4u..4u+3)
    float o0 = lin_b[0], o1 = lin_b[1];
#pragma unroll
    for (int k = 0; k < 16; ++k) {
        float hk = rl_f(hv, 4 * k);
        o0 = fmaf(hk, lin_w[k],      o0);
        o1 = fmaf(hk, lin_w[16 + k], o1);
    }
    if (lane == 0) {
        reinterpret_cast<float2*>(out)[b] = make_float2(o0, o1);
    }
}

extern "C" void kernel_launch(void* const* d_in, const int* in_sizes, int n_in,
                              void* d_out, int out_size, void* d_ws, size_t ws_size,
                              hipStream_t stream) {
    const float* x      = (const float*)d_in[0];
    const int*   x_lens = (const int*)  d_in[1];
    const float* W_ih   = (const float*)d_in[2];
    const float* W_hh   = (const float*)d_in[3];
    const float* b_ih   = (const float*)d_in[4];
    const float* b_hh   = (const float*)d_in[5];
    const float* lin_w  = (const float*)d_in[6];
    const float* lin_b  = (const float*)d_in[7];
    float* out = (float*)d_out;

    const int B = in_sizes[1];
    const int T = in_sizes[0] / B;

    lstm_seq_kernel<<<B, 64, 0, stream>>>(x, x_lens, W_ih, W_hh, b_ih, b_hh,
                                          lin_w, lin_b, out, T);
}